// Round 1
// 408.157 us; speedup vs baseline: 1.0105x; 1.0105x over previous
//
#include <hip/hip_runtime.h>
#include <math.h>

#define B_ 4
#define S_ 2048
#define H_ 768
#define NH_ 12
#define HD_ 64
#define BSH (B_ * S_ * H_)
#define NROWS (B_ * S_)
#define WSZ (H_ * H_)  // 589824

typedef __attribute__((ext_vector_type(8))) short bf16x8;
typedef __attribute__((ext_vector_type(4))) short s16x4;
typedef __attribute__((ext_vector_type(4))) float f32x4;
typedef __attribute__((ext_vector_type(2))) unsigned u32x2;

__device__ __forceinline__ short f2bf(float f) {
  union { float f; unsigned u; } x; x.f = f;
  unsigned r = x.u + 0x7FFF + ((x.u >> 16) & 1);
  return (short)(r >> 16);
}
__device__ __forceinline__ float bf2f(short s) {
  union { unsigned u; float f; } x;
  x.u = ((unsigned)(unsigned short)s) << 16;
  return x.f;
}
// pack 2 fp32 -> 2 bf16 (truncation) in one v_perm_b32
__device__ __forceinline__ unsigned bfpack(float lo, float hi) {
  union { float f; unsigned u; } a, b; a.f = lo; b.f = hi;
  return __builtin_amdgcn_perm(b.u, a.u, 0x07060302);
}

// async global->LDS, 16B per lane; LDS dst = wave-uniform base + lane*16
typedef __attribute__((address_space(1))) const unsigned int g_u32;
typedef __attribute__((address_space(3))) unsigned int l_u32;
__device__ __forceinline__ void gload16(const void* g, void* l) {
  __builtin_amdgcn_global_load_lds((g_u32*)g, (l_u32*)l, 16, 0, 0);
}

// ---------------------------------------------------------------------------
// fp32 -> bf16 converters
// ---------------------------------------------------------------------------
__global__ __launch_bounds__(256) void cvt_x_k(const float* __restrict__ src,
                                               short* __restrict__ dst) {
  int i = (blockIdx.x * 256 + threadIdx.x) * 4;
  float4 v = *(const float4*)(src + i);
  s16x4 o = {f2bf(v.x), f2bf(v.y), f2bf(v.z), f2bf(v.w)};
  *(s16x4*)(dst + i) = o;
}

__global__ __launch_bounds__(256) void cvt6_k(const float* w0, const float* w1,
                                              const float* w2, const float* w3,
                                              const float* w4, const float* w5,
                                              short* __restrict__ dst) {
  int i = (blockIdx.x * 256 + threadIdx.x) * 4;
  int m = i / WSZ;
  int off = i - m * WSZ;
  const float* s = m == 0 ? w0 : m == 1 ? w1 : m == 2 ? w2 : m == 3 ? w3 : m == 4 ? w4 : w5;
  float4 v = *(const float4*)(s + off);
  s16x4 o = {f2bf(v.x), f2bf(v.y), f2bf(v.z), f2bf(v.w)};
  *(s16x4*)(dst + i) = o;
}

// ---------------------------------------------------------------------------
// depthwise conv1d k=3 pad=1 over seq; vectorized x4, 192 thr (H/4=192)
// ---------------------------------------------------------------------------
__global__ __launch_bounds__(192) void dwconv_k(const float* __restrict__ prev,
                                                const float* __restrict__ w3,
                                                const float* __restrict__ bias,
                                                short* __restrict__ out) {
  int row = blockIdx.x;
  int s = row & (S_ - 1);
  int h = threadIdx.x * 4;
  size_t base = (size_t)row * H_ + h;
  float4 c = *(const float4*)(prev + base);
  float4 wa = *(const float4*)(w3 + h * 3);
  float4 wb = *(const float4*)(w3 + h * 3 + 4);
  float4 wc = *(const float4*)(w3 + h * 3 + 8);
  float4 bi = *(const float4*)(bias + h);
  float4 acc;
  acc.x = bi.x + c.x * wa.y;
  acc.y = bi.y + c.y * wb.x;
  acc.z = bi.z + c.z * wb.w;
  acc.w = bi.w + c.w * wc.z;
  if (s > 0) {
    float4 l = *(const float4*)(prev + base - H_);
    acc.x += l.x * wa.x; acc.y += l.y * wa.w; acc.z += l.z * wb.z; acc.w += l.w * wc.y;
  }
  if (s < S_ - 1) {
    float4 r = *(const float4*)(prev + base + H_);
    acc.x += r.x * wa.z; acc.y += r.y * wb.y; acc.z += r.z * wc.x; acc.w += r.w * wc.w;
  }
  s16x4 o = {f2bf(acc.x), f2bf(acc.y), f2bf(acc.z), f2bf(acc.w)};
  *(s16x4*)(out + base) = o;
}

// ---------------------------------------------------------------------------
// Grouped GEMM (QKV): 128x128 tiles, BK=64, blockIdx.z selects job.
// ---------------------------------------------------------------------------
struct GemmJob {
  const short* A; const short* W; const float* bias; short* C; int act; int tout;
};

__global__ __launch_bounds__(256) void gemm_bf2(GemmJob j0, GemmJob j1, GemmJob j2) {
  GemmJob j = blockIdx.z == 0 ? j0 : (blockIdx.z == 1 ? j1 : j2);
  __shared__ short As[128 * 64];  // 16 KB
  __shared__ short Ws[128 * 64];
  int tid = threadIdx.x, lane = tid & 63, w = tid >> 6;
  int wr = w >> 1, wc = w & 1, lm = lane & 15, lq = lane >> 4;
  int m0 = blockIdx.y * 128, n0 = blockIdx.x * 128;
  int srow = lane >> 3;
  int skc = (lane & 7) * 8;
  const short* gA = j.A + (size_t)(m0 + w * 32 + srow) * H_ + skc;
  const short* gW = j.W + (size_t)(n0 + w * 32 + srow) * H_ + skc;
  short* lA = As + w * 2048;
  short* lW = Ws + w * 2048;

  f32x4 acc[4][4];
#pragma unroll
  for (int i = 0; i < 4; ++i)
#pragma unroll
    for (int jj = 0; jj < 4; ++jj) acc[i][jj] = (f32x4){0.f, 0.f, 0.f, 0.f};

  for (int kt = 0; kt < H_; kt += 64) {
    __syncthreads();
#pragma unroll
    for (int c = 0; c < 4; ++c) {
      gload16(gA + kt + (size_t)(c * 8) * H_, lA + c * 512);
      gload16(gW + kt + (size_t)(c * 8) * H_, lW + c * 512);
    }
    __syncthreads();
#pragma unroll
    for (int kk = 0; kk < 2; ++kk) {
      bf16x8 af[4], wf[4];
#pragma unroll
      for (int i = 0; i < 4; ++i)
        af[i] = *(const bf16x8*)&As[(wr * 64 + i * 16 + lm) * 64 + kk * 32 + lq * 8];
#pragma unroll
      for (int jj = 0; jj < 4; ++jj)
        wf[jj] = *(const bf16x8*)&Ws[(wc * 64 + jj * 16 + lm) * 64 + kk * 32 + lq * 8];
#pragma unroll
      for (int i = 0; i < 4; ++i)
#pragma unroll
        for (int jj = 0; jj < 4; ++jj)
          acc[i][jj] = __builtin_amdgcn_mfma_f32_16x16x32_bf16(af[i], wf[jj], acc[i][jj], 0, 0, 0);
    }
  }

  if (!j.tout) {
#pragma unroll
    for (int jj = 0; jj < 4; ++jj) {
      int col = n0 + wc * 64 + jj * 16 + lm;
      float bn = j.bias[col];
#pragma unroll
      for (int i = 0; i < 4; ++i) {
        int mrow = m0 + wr * 64 + i * 16 + lq * 4;
#pragma unroll
        for (int r = 0; r < 4; ++r) {
          float cv = acc[i][jj][r] + bn;
          if (j.act) cv = 0.5f * cv * (1.0f + erff(cv * 0.70710678118f));
          j.C[(size_t)(mrow + r) * H_ + col] = f2bf(cv);
        }
      }
    }
  } else {
    int b = m0 >> 11;
    int sb = (m0 & (S_ - 1)) + wr * 64;
#pragma unroll
    for (int jj = 0; jj < 4; ++jj) {
      int col = n0 + wc * 64 + jj * 16 + lm;
      float bn = j.bias[col];
      short* cp = j.C + ((size_t)(b * H_ + col)) * S_;
#pragma unroll
      for (int i = 0; i < 4; ++i) {
        int s = sb + i * 16 + lq * 4;
        s16x4 pk = {f2bf(acc[i][jj][0] + bn), f2bf(acc[i][jj][1] + bn),
                    f2bf(acc[i][jj][2] + bn), f2bf(acc[i][jj][3] + bn)};
        *(s16x4*)(cp + s) = pk;
      }
    }
  }
}

// ---------------------------------------------------------------------------
// Single GEMM, 128x64 tile (768 blocks = 3.0/CU): pw/o/post projections.
// 4 waves: 2 m-halves x 2 n-halves; wave = 64m x 32n, acc 4x2.
// ---------------------------------------------------------------------------
__global__ __launch_bounds__(256) void gemm_n64(const short* __restrict__ A,
                                                const short* __restrict__ W,
                                                const float* __restrict__ bias,
                                                short* __restrict__ C, int act) {
  __shared__ short As[128 * 64];  // 16 KB
  __shared__ short Ws[64 * 64];   // 8 KB
  int tid = threadIdx.x, lane = tid & 63, w = tid >> 6;
  int wm = w >> 1, wn = w & 1, lm = lane & 15, lq = lane >> 4;
  int m0 = blockIdx.y * 128, n0 = blockIdx.x * 64;
  const short* gA = A + (size_t)(m0 + w * 32 + (lane >> 3)) * H_ + (lane & 7) * 8;
  const short* gW = W + (size_t)(n0 + w * 16 + (lane >> 3)) * H_ + (lane & 7) * 8;
  short* lA = As + w * 2048;  // 32 rows x 64
  short* lW = Ws + w * 1024;  // 16 rows x 64

  f32x4 acc[4][2];
#pragma unroll
  for (int i = 0; i < 4; ++i)
#pragma unroll
    for (int jj = 0; jj < 2; ++jj) acc[i][jj] = (f32x4){0.f, 0.f, 0.f, 0.f};

  for (int kt = 0; kt < H_; kt += 64) {
    __syncthreads();
#pragma unroll
    for (int c = 0; c < 4; ++c)
      gload16(gA + kt + (size_t)(c * 8) * H_, lA + c * 512);
#pragma unroll
    for (int c = 0; c < 2; ++c)
      gload16(gW + kt + (size_t)(c * 8) * H_, lW + c * 512);
    __syncthreads();
#pragma unroll
    for (int kk = 0; kk < 2; ++kk) {
      bf16x8 af[4], wf[2];
#pragma unroll
      for (int i = 0; i < 4; ++i)
        af[i] = *(const bf16x8*)&As[(wm * 64 + i * 16 + lm) * 64 + kk * 32 + lq * 8];
#pragma unroll
      for (int jj = 0; jj < 2; ++jj)
        wf[jj] = *(const bf16x8*)&Ws[(wn * 32 + jj * 16 + lm) * 64 + kk * 32 + lq * 8];
#pragma unroll
      for (int i = 0; i < 4; ++i)
#pragma unroll
        for (int jj = 0; jj < 2; ++jj)
          acc[i][jj] = __builtin_amdgcn_mfma_f32_16x16x32_bf16(af[i], wf[jj], acc[i][jj], 0, 0, 0);
    }
  }

#pragma unroll
  for (int jj = 0; jj < 2; ++jj) {
    int col = n0 + wn * 32 + jj * 16 + lm;
    float bn = bias[col];
#pragma unroll
    for (int i = 0; i < 4; ++i) {
      int mrow = m0 + wm * 64 + i * 16 + lq * 4;
#pragma unroll
      for (int r = 0; r < 4; ++r) {
        float cv = acc[i][jj][r] + bn;
        if (act) cv = 0.5f * cv * (1.0f + erff(cv * 0.70710678118f));
        C[(size_t)(mrow + r) * H_ + col] = f2bf(cv);
      }
    }
  }
}

// ---------------------------------------------------------------------------
// LayerNorm over last dim (H=768), bf16 in -> bf16 out
// ---------------------------------------------------------------------------
__global__ __launch_bounds__(256) void ln_bf(const short* __restrict__ X,
                                             short* __restrict__ Y,
                                             const float* __restrict__ g,
                                             const float* __restrict__ bb) {
  int row = blockIdx.x;
  size_t base = (size_t)row * H_;
  int h0 = threadIdx.x, h1 = h0 + 256, h2 = h0 + 512;
  float x0 = bf2f(X[base + h0]), x1 = bf2f(X[base + h1]), x2 = bf2f(X[base + h2]);
  float s = x0 + x1 + x2;
  float s2 = x0 * x0 + x1 * x1 + x2 * x2;
  for (int off = 32; off > 0; off >>= 1) {
    s += __shfl_down(s, off);
    s2 += __shfl_down(s2, off);
  }
  __shared__ float sa[4], sq[4], st[2];
  int wid = threadIdx.x >> 6, lane = threadIdx.x & 63;
  if (lane == 0) { sa[wid] = s; sq[wid] = s2; }
  __syncthreads();
  if (threadIdx.x == 0) {
    float ts = sa[0] + sa[1] + sa[2] + sa[3];
    float ts2 = sq[0] + sq[1] + sq[2] + sq[3];
    float mean = ts * (1.0f / H_);
    float var = ts2 * (1.0f / H_) - mean * mean;
    st[0] = mean;
    st[1] = rsqrtf(var + 1e-5f);
  }
  __syncthreads();
  float mean = st[0], rstd = st[1];
  Y[base + h0] = f2bf((x0 - mean) * rstd * g[h0] + bb[h0]);
  Y[base + h1] = f2bf((x1 - mean) * rstd * g[h1] + bb[h1]);
  Y[base + h2] = f2bf((x2 - mean) * rstd * g[h2] + bb[h2]);
}

// ---------------------------------------------------------------------------
// MFMA flash attention v5: 256 thr = 4 waves x 32 q-rows (2 q-groups/wave).
// Changes vs v4:
//  - All LDS tiles at natural pitch 64 shorts (128B rows) with 16B-slot XOR
//    swizzle (slot ^= row&7): every b128 fragment read / staging write / b64
//    P write is bank-conflict-free (v4's pitch-72 gave 8-way aliasing, 1.1e7
//    SQ_LDS_BANK_CONFLICT). LDS 36KB -> 32KB.
//  - Softmax denominator moved off the VALU onto the matrix pipe: ones-A
//    MFMA pair per q-group accumulates column sums of P^T (every output row
//    = sum), replacing 12 adds + 2 shuffles per q-group per tile.
// ---------------------------------------------------------------------------
__global__ __launch_bounds__(256) void attn5_k(const short* __restrict__ qb,
                                               const short* __restrict__ kb,
                                               const short* __restrict__ vtb,
                                               short* __restrict__ aob) {
  __shared__ short Ks[64 * 64];        // [sk][d] swizzled, 8 KB
  __shared__ short Vt[64 * 64];        // [d][sk] swizzled, 8 KB
  __shared__ short Ps[128 * 64];       // wave w rows [w*32, +32), swizzled, 16 KB
  int tid = threadIdx.x, lane = tid & 63, w = tid >> 6;  // w 0..3
  int lm = lane & 15, lq = lane >> 4;
  int lm7 = lm & 7;
  int b = blockIdx.z, n = blockIdx.y, q0 = blockIdx.x * 128;
  int hoff = n * HD_;

  // swizzled fragment slot offsets (in shorts): logical 16B-slot lq / lq+4
  int rb8 = (lq ^ lm7) << 3;    // slot lq  -> phys
  int rb8x = rb8 ^ 32;          // slot lq+4 -> phys (== ((lq^4)^lm7)<<3)

  bf16x8 qf[2][2];
#pragma unroll
  for (int qg = 0; qg < 2; ++qg) {
    const short* qrow = qb + ((size_t)(b * S_ + q0 + w * 32 + qg * 16 + lm)) * H_ + hoff;
    qf[qg][0] = *(const bf16x8*)(qrow + lq * 8);
    qf[qg][1] = *(const bf16x8*)(qrow + 32 + lq * 8);
  }

  // ones A-fragment (bf16 1.0) for MFMA row-sum of P
  bf16x8 onef = {0x3F80, 0x3F80, 0x3F80, 0x3F80, 0x3F80, 0x3F80, 0x3F80, 0x3F80};
  f32x4 ls[2];
  ls[0] = (f32x4){0.f, 0.f, 0.f, 0.f};
  ls[1] = (f32x4){0.f, 0.f, 0.f, 0.f};

  f32x4 o[4][2];
#pragma unroll
  for (int i = 0; i < 4; ++i)
#pragma unroll
    for (int qg = 0; qg < 2; ++qg) o[i][qg] = (f32x4){0.f, 0.f, 0.f, 0.f};

  // staging: row = tid>>2 (0..63), 2x16B each of K,V at logical slots 2j, 2j+1
  int r0 = tid >> 2;
  int c0 = (tid & 3) * 16;                       // logical short col (global addr)
  int sl = (tid & 3) * 2;                        // logical 16B slot
  int sw0 = r0 * 64 + ((sl ^ (r0 & 7)) << 3);    // phys short offset, slot sl
  int sw1 = r0 * 64 + (((sl ^ 1) ^ (r0 & 7)) << 3);  // slot sl+1 (sl even)
  const short* kg = kb + ((size_t)(b * S_)) * H_ + hoff;
  const short* vg = vtb + ((size_t)(b * H_ + hoff)) * S_;
  const float C1 = 0.1803368802f;  // 0.125 * log2(e)

  bf16x8 kv0 = *(const bf16x8*)(kg + (size_t)r0 * H_ + c0);
  bf16x8 kv1 = *(const bf16x8*)(kg + (size_t)r0 * H_ + c0 + 8);
  bf16x8 vv0 = *(const bf16x8*)(vg + (size_t)r0 * S_ + c0);
  bf16x8 vv1 = *(const bf16x8*)(vg + (size_t)r0 * S_ + c0 + 8);

  for (int kt = 0; kt < S_; kt += 64) {
    __syncthreads();
    *(bf16x8*)&Ks[sw0] = kv0;
    *(bf16x8*)&Ks[sw1] = kv1;
    *(bf16x8*)&Vt[sw0] = vv0;
    *(bf16x8*)&Vt[sw1] = vv1;
    __syncthreads();
    if (kt + 64 < S_) {
      kv0 = *(const bf16x8*)(kg + (size_t)(kt + 64 + r0) * H_ + c0);
      kv1 = *(const bf16x8*)(kg + (size_t)(kt + 64 + r0) * H_ + c0 + 8);
      vv0 = *(const bf16x8*)(vg + (size_t)r0 * S_ + kt + 64 + c0);
      vv1 = *(const bf16x8*)(vg + (size_t)r0 * S_ + kt + 64 + c0 + 8);
    }

    // ---- S^T[sk][q]: sk = ni*16 + lq*4 + r, q = lm (per q-group) ----
    f32x4 st[4][2];
#pragma unroll
    for (int ni = 0; ni < 4; ++ni) {
      int krow = (ni * 16 + lm) * 64;
      bf16x8 ka0 = *(const bf16x8*)&Ks[krow + rb8];
      bf16x8 ka1 = *(const bf16x8*)&Ks[krow + rb8x];
#pragma unroll
      for (int qg = 0; qg < 2; ++qg) {
        f32x4 z = (f32x4){0.f, 0.f, 0.f, 0.f};
        z = __builtin_amdgcn_mfma_f32_16x16x32_bf16(ka0, qf[qg][0], z, 0, 0, 0);
        st[ni][qg] = __builtin_amdgcn_mfma_f32_16x16x32_bf16(ka1, qf[qg][1], z, 0, 0, 0);
      }
    }

    // ---- softmax numerator + P pack via v_perm (sum via MFMA below) ----
#pragma unroll
    for (int qg = 0; qg < 2; ++qg) {
      int prow = (w * 32 + qg * 16 + lm) * 64 + (lq & 1) * 4;
      int lqh = lq >> 1;
#pragma unroll
      for (int ni = 0; ni < 4; ++ni) {
        float p0 = exp2f(st[ni][qg][0] * C1);
        float p1 = exp2f(st[ni][qg][1] * C1);
        float p2 = exp2f(st[ni][qg][2] * C1);
        float p3 = exp2f(st[ni][qg][3] * C1);
        u32x2 pk = {bfpack(p0, p1), bfpack(p2, p3)};
        *(u32x2*)&Ps[prow + (((2 * ni + lqh) ^ lm7) << 3)] = pk;
      }
    }

    // ---- O^T += V^T P^T ; denominator += 1^T P^T (matrix pipe) ----
    bf16x8 pf[2][2];
#pragma unroll
    for (int qg = 0; qg < 2; ++qg) {
      int prow = (w * 32 + qg * 16 + lm) * 64;
      pf[qg][0] = *(const bf16x8*)&Ps[prow + rb8];
      pf[qg][1] = *(const bf16x8*)&Ps[prow + rb8x];
      ls[qg] = __builtin_amdgcn_mfma_f32_16x16x32_bf16(onef, pf[qg][0], ls[qg], 0, 0, 0);
      ls[qg] = __builtin_amdgcn_mfma_f32_16x16x32_bf16(onef, pf[qg][1], ls[qg], 0, 0, 0);
    }
#pragma unroll
    for (int nd = 0; nd < 4; ++nd) {
      int vrow = (nd * 16 + lm) * 64;
      bf16x8 va0 = *(const bf16x8*)&Vt[vrow + rb8];
      bf16x8 va1 = *(const bf16x8*)&Vt[vrow + rb8x];
#pragma unroll
      for (int qg = 0; qg < 2; ++qg) {
        o[nd][qg] = __builtin_amdgcn_mfma_f32_16x16x32_bf16(va0, pf[qg][0], o[nd][qg], 0, 0, 0);
        o[nd][qg] = __builtin_amdgcn_mfma_f32_16x16x32_bf16(va1, pf[qg][1], o[nd][qg], 0, 0, 0);
      }
    }
  }

  // epilogue: q row = q0 + w*32 + qg*16 + lm; d = nd*16 + lq*4 + r
#pragma unroll
  for (int qg = 0; qg < 2; ++qg) {
    float inv = 1.0f / ls[qg][0];
    short* orow = aob + ((size_t)(b * S_ + q0 + w * 32 + qg * 16 + lm)) * H_ + hoff;
#pragma unroll
    for (int nd = 0; nd < 4; ++nd) {
      s16x4 pk = {f2bf(o[nd][qg][0] * inv), f2bf(o[nd][qg][1] * inv),
                  f2bf(o[nd][qg][2] * inv), f2bf(o[nd][qg][3] * inv)};
      *(s16x4*)(orow + nd * 16 + lq * 4) = pk;
    }
  }
}

// ---------------------------------------------------------------------------
// gate + masked residual + aux partials. 192 thr, x4 vectorized.
// ---------------------------------------------------------------------------
__global__ __launch_bounds__(192) void gate_out_k(const float* __restrict__ x,
                                                  const short* __restrict__ br,
                                                  const short* __restrict__ inj,
                                                  const int* __restrict__ mask,
                                                  const float* __restrict__ Wg,
                                                  const float* __restrict__ bg,
                                                  float* __restrict__ out,
                                                  float* __restrict__ paux) {
  int row = blockIdx.x;
  int b = row >> 11;
  size_t base = (size_t)row * H_;
  int h = threadIdx.x * 4;
  float4 xv = *(const float4*)(x + base + h);
  s16x4 brv = *(const s16x4*)(br + base + h);
  s16x4 inv = *(const s16x4*)(inj + base + h);
  float4 wg0 = *(const float4*)(Wg + h);
  float4 wg1 = *(const float4*)(Wg + H_ + h);
  float b0 = bf2f(brv.x), b1 = bf2f(brv.y), b2 = bf2f(brv.z), b3 = bf2f(brv.w);
  float dot = xv.x * wg0.x + xv.y * wg0.y + xv.z * wg0.z + xv.w * wg0.w
            + b0 * wg1.x + b1 * wg1.y + b2 * wg1.z + b3 * wg1.w;
  float d0 = b0 - xv.x, d1 = b1 - xv.y, d2 = b2 - xv.z, d3 = b3 - xv.w;
  float aux = d0 * d0 + d1 * d1 + d2 * d2 + d3 * d3;
  for (int off = 32; off > 0; off >>= 1) {
    dot += __shfl_down(dot, off);
    aux += __shfl_down(aux, off);
  }
  __shared__ float sd[3], sx[3], gsh[2];
  int wid = threadIdx.x >> 6, lane = threadIdx.x & 63;
  if (lane == 0) { sd[wid] = dot; sx[wid] = aux; }
  __syncthreads();
  if (threadIdx.x == 0) {
    float td = sd[0] + sd[1] + sd[2];
    float ta = sx[0] + sx[1] + sx[2];
    gsh[0] = 1.0f / (1.0f + expf(-(td + bg[0])));
    gsh[1] = ta;
  }
  __syncthreads();
  float mf = (mask[b] != 0) ? 1.0f : 0.0f;
  float gm = gsh[0] * mf;
  float v0 = bf2f(inv.x), v1 = bf2f(inv.y), v2 = bf2f(inv.z), v3 = bf2f(inv.w);
  float e0 = __expf(2.f * v0), e1 = __expf(2.f * v1), e2 = __expf(2.f * v2), e3 = __expf(2.f * v3);
  float4 ov;
  ov.x = xv.x + gm * ((e0 - 1.f) / (e0 + 1.f));
  ov.y = xv.y + gm * ((e1 - 1.f) / (e1 + 1.f));
  ov.z = xv.z + gm * ((e2 - 1.f) / (e2 + 1.f));
  ov.w = xv.w + gm * ((e3 - 1.f) / (e3 + 1.f));
  *(float4*)(out + base + h) = ov;
  if (threadIdx.x == 0) paux[row] = mf * gsh[1];
}

__global__ __launch_bounds__(256) void aux_reduce_k(const float* __restrict__ paux,
                                                    const int* __restrict__ mask,
                                                    float* __restrict__ outp) {
  float s = 0.f;
  for (int i = threadIdx.x; i < NROWS; i += 256) s += paux[i];
  for (int off = 32; off > 0; off >>= 1) s += __shfl_down(s, off);
  __shared__ float sw[4];
  int wid = threadIdx.x >> 6, lane = threadIdx.x & 63;
  if (lane == 0) sw[wid] = s;
  __syncthreads();
  if (threadIdx.x == 0) {
    float t = sw[0] + sw[1] + sw[2] + sw[3];
    int nm = (mask[0] != 0) + (mask[1] != 0) + (mask[2] != 0) + (mask[3] != 0);
    if (nm < 1) nm = 1;
    outp[0] = t / ((float)nm * (float)(S_ * H_));
  }
}

// ---------------------------------------------------------------------------
extern "C" void kernel_launch(void* const* d_in, const int* in_sizes, int n_in,
                              void* d_out, int out_size, void* d_ws, size_t ws_size,
                              hipStream_t stream) {
  const float* x     = (const float*)d_in[0];
  const float* prev  = (const float*)d_in[1];
  const int*   mask  = (const int*)d_in[2];
  const float* dw_w  = (const float*)d_in[3];
  const float* dw_b  = (const float*)d_in[4];
  const float* pw_w  = (const float*)d_in[5];
  const float* pw_b  = (const float*)d_in[6];
  const float* cn_g  = (const float*)d_in[7];
  const float* cn_b  = (const float*)d_in[8];
  const float* Wq    = (const float*)d_in[9];
  const float* bq    = (const float*)d_in[10];
  const float* Wk    = (const float*)d_in[11];
  const float* bk    = (const float*)d_in[12];
  const float* Wv    = (const float*)d_in[13];
  const float* bv    = (const float*)d_in[14];
  const float* Wo    = (const float*)d_in[15];
  const float* bo    = (const float*)d_in[16];
  const float* pn_g  = (const float*)d_in[17];
  const float* pn_b  = (const float*)d_in[18];
  const float* Wpost = (const float*)d_in[19];
  const float* bpost = (const float*)d_in[20];
  const float* Wg    = (const float*)d_in[21];
  const float* bg    = (const float*)d_in[22];
  float* out = (float*)d_out;

  short* B0 = (short*)d_ws;     // xb
  short* B1 = B0 + BSH;         // dwo -> qb
  short* B2 = B1 + BSH;         // gelu-out -> aob
  short* B3 = B2 + BSH;         // bridged (until gate)
  short* B4 = B3 + BSH;         // kb -> ao_proj -> pn
  short* B5 = B4 + BSH;         // vtb -> injb
  short* WW = B5 + BSH;         // 6 bf16 weights [pw,q,k,v,o,post]
  float* paux = (float*)(WW + 6 * WSZ);

  dim3 g3(H_ / 128, NROWS / 128, 3);   // QKV grouped
  dim3 gn(H_ / 64, NROWS / 128, 1);    // (12, 64) single GEMMs

  GemmJob jq = {B0, WW + WSZ,     bq, B1, 0, 0};
  GemmJob jk = {B3, WW + 2 * WSZ, bk, B4, 0, 0};
  GemmJob jv = {B3, WW + 3 * WSZ, bv, B5, 0, 1};

  cvt6_k<<<6 * WSZ / 1024, 256, 0, stream>>>(pw_w, Wq, Wk, Wv, Wo, Wpost, WW);
  cvt_x_k<<<BSH / 1024, 256, 0, stream>>>(x, B0);
  dwconv_k<<<NROWS, 192, 0, stream>>>(prev, dw_w, dw_b, B1);
  gemm_n64<<<gn, 256, 0, stream>>>(B1, WW, pw_b, B2, 1);                   // pw + GELU
  ln_bf<<<NROWS, 256, 0, stream>>>(B2, B3, cn_g, cn_b);                    // bridged
  gemm_bf2<<<g3, 256, 0, stream>>>(jq, jk, jv);                            // Q,K,V grouped
  attn5_k<<<dim3(S_ / 128, NH_, B_), 256, 0, stream>>>(B1, B4, B5, B2);    // -> aob
  gemm_n64<<<gn, 256, 0, stream>>>(B2, WW + 4 * WSZ, bo, B4, 0);           // o-proj
  ln_bf<<<NROWS, 256, 0, stream>>>(B4, B4, pn_g, pn_b);                    // pn
  gemm_n64<<<gn, 256, 0, stream>>>(B4, WW + 5 * WSZ, bpost, B5, 0);        // post
  gate_out_k<<<NROWS, 192, 0, stream>>>(x, B3, B5, mask, Wg, bg, out, paux);
  aux_reduce_k<<<1, 256, 0, stream>>>(paux, mask, out + BSH);
}

// Round 2
// 389.248 us; speedup vs baseline: 1.0596x; 1.0486x over previous
//
#include <hip/hip_runtime.h>
#include <math.h>

#define B_ 4
#define S_ 2048
#define H_ 768
#define NH_ 12
#define HD_ 64
#define BSH (B_ * S_ * H_)
#define NROWS (B_ * S_)
#define WSZ (H_ * H_)  // 589824

typedef __attribute__((ext_vector_type(8))) short bf16x8;
typedef __attribute__((ext_vector_type(4))) short s16x4;
typedef __attribute__((ext_vector_type(4))) float f32x4;
typedef __attribute__((ext_vector_type(2))) unsigned u32x2;

__device__ __forceinline__ short f2bf(float f) {
  union { float f; unsigned u; } x; x.f = f;
  unsigned r = x.u + 0x7FFF + ((x.u >> 16) & 1);
  return (short)(r >> 16);
}
__device__ __forceinline__ float bf2f(short s) {
  union { unsigned u; float f; } x;
  x.u = ((unsigned)(unsigned short)s) << 16;
  return x.f;
}
// pack 2 fp32 -> 2 bf16 (truncation) in one v_perm_b32
__device__ __forceinline__ unsigned bfpack(float lo, float hi) {
  union { float f; unsigned u; } a, b; a.f = lo; b.f = hi;
  return __builtin_amdgcn_perm(b.u, a.u, 0x07060302);
}

// async global->LDS, 16B per lane; LDS dst = wave-uniform base + lane*16
typedef __attribute__((address_space(1))) const unsigned int g_u32;
typedef __attribute__((address_space(3))) unsigned int l_u32;
__device__ __forceinline__ void gload16(const void* g, void* l) {
  __builtin_amdgcn_global_load_lds((g_u32*)g, (l_u32*)l, 16, 0, 0);
}

// ---------------------------------------------------------------------------
// fp32 -> bf16 converters
// ---------------------------------------------------------------------------
__global__ __launch_bounds__(256) void cvt_x_k(const float* __restrict__ src,
                                               short* __restrict__ dst) {
  int i = (blockIdx.x * 256 + threadIdx.x) * 4;
  float4 v = *(const float4*)(src + i);
  s16x4 o = {f2bf(v.x), f2bf(v.y), f2bf(v.z), f2bf(v.w)};
  *(s16x4*)(dst + i) = o;
}

// w1 (Wq) is pre-scaled by C1 = 0.125*log2(e) so attn can exp2 scores directly
__global__ __launch_bounds__(256) void cvt6_k(const float* w0, const float* w1,
                                              const float* w2, const float* w3,
                                              const float* w4, const float* w5,
                                              short* __restrict__ dst) {
  int i = (blockIdx.x * 256 + threadIdx.x) * 4;
  int m = i / WSZ;
  int off = i - m * WSZ;
  const float* s = m == 0 ? w0 : m == 1 ? w1 : m == 2 ? w2 : m == 3 ? w3 : m == 4 ? w4 : w5;
  float sc = (m == 1) ? 0.1803368802f : 1.0f;
  float4 v = *(const float4*)(s + off);
  s16x4 o = {f2bf(v.x * sc), f2bf(v.y * sc), f2bf(v.z * sc), f2bf(v.w * sc)};
  *(s16x4*)(dst + i) = o;
}

// ---------------------------------------------------------------------------
// depthwise conv1d k=3 pad=1 over seq; vectorized x4, 192 thr (H/4=192)
// ---------------------------------------------------------------------------
__global__ __launch_bounds__(192) void dwconv_k(const float* __restrict__ prev,
                                                const float* __restrict__ w3,
                                                const float* __restrict__ bias,
                                                short* __restrict__ out) {
  int row = blockIdx.x;
  int s = row & (S_ - 1);
  int h = threadIdx.x * 4;
  size_t base = (size_t)row * H_ + h;
  float4 c = *(const float4*)(prev + base);
  float4 wa = *(const float4*)(w3 + h * 3);
  float4 wb = *(const float4*)(w3 + h * 3 + 4);
  float4 wc = *(const float4*)(w3 + h * 3 + 8);
  float4 bi = *(const float4*)(bias + h);
  float4 acc;
  acc.x = bi.x + c.x * wa.y;
  acc.y = bi.y + c.y * wb.x;
  acc.z = bi.z + c.z * wb.w;
  acc.w = bi.w + c.w * wc.z;
  if (s > 0) {
    float4 l = *(const float4*)(prev + base - H_);
    acc.x += l.x * wa.x; acc.y += l.y * wa.w; acc.z += l.z * wb.z; acc.w += l.w * wc.y;
  }
  if (s < S_ - 1) {
    float4 r = *(const float4*)(prev + base + H_);
    acc.x += r.x * wa.z; acc.y += r.y * wb.y; acc.z += r.z * wc.x; acc.w += r.w * wc.w;
  }
  s16x4 o = {f2bf(acc.x), f2bf(acc.y), f2bf(acc.z), f2bf(acc.w)};
  *(s16x4*)(out + base) = o;
}

// ---------------------------------------------------------------------------
// Grouped GEMM (QKV): 128x128 tiles, BK=64. 1D grid, XCD-swizzled so all
// blocks sharing an A row-panel land on one XCD (same L2).
// ---------------------------------------------------------------------------
struct GemmJob {
  const short* A; const short* W; const float* bias; short* C; int act; int tout;
  float bscale;
};

__global__ __launch_bounds__(256) void gemm_bf2(GemmJob j0, GemmJob j1, GemmJob j2) {
  int d = blockIdx.x;
  int z = d / 384, r5 = d - z * 384;
  GemmJob j = z == 0 ? j0 : (z == 1 ? j1 : j2);
  int xcd = r5 & 7, s5 = r5 >> 3;          // s5 in [0,48)
  int nx = s5 % 6, ny = xcd + 8 * (s5 / 6);  // ny in [0,64)
  __shared__ short As[128 * 64];  // 16 KB
  __shared__ short Ws[128 * 64];
  int tid = threadIdx.x, lane = tid & 63, w = tid >> 6;
  int wr = w >> 1, wc = w & 1, lm = lane & 15, lq = lane >> 4;
  int m0 = ny * 128, n0 = nx * 128;
  int srow = lane >> 3;
  int skc = (lane & 7) * 8;
  const short* gA = j.A + (size_t)(m0 + w * 32 + srow) * H_ + skc;
  const short* gW = j.W + (size_t)(n0 + w * 32 + srow) * H_ + skc;
  short* lA = As + w * 2048;
  short* lW = Ws + w * 2048;

  f32x4 acc[4][4];
#pragma unroll
  for (int i = 0; i < 4; ++i)
#pragma unroll
    for (int jj = 0; jj < 4; ++jj) acc[i][jj] = (f32x4){0.f, 0.f, 0.f, 0.f};

  for (int kt = 0; kt < H_; kt += 64) {
    __syncthreads();
#pragma unroll
    for (int c = 0; c < 4; ++c) {
      gload16(gA + kt + (size_t)(c * 8) * H_, lA + c * 512);
      gload16(gW + kt + (size_t)(c * 8) * H_, lW + c * 512);
    }
    __syncthreads();
#pragma unroll
    for (int kk = 0; kk < 2; ++kk) {
      bf16x8 af[4], wf[4];
#pragma unroll
      for (int i = 0; i < 4; ++i)
        af[i] = *(const bf16x8*)&As[(wr * 64 + i * 16 + lm) * 64 + kk * 32 + lq * 8];
#pragma unroll
      for (int jj = 0; jj < 4; ++jj)
        wf[jj] = *(const bf16x8*)&Ws[(wc * 64 + jj * 16 + lm) * 64 + kk * 32 + lq * 8];
#pragma unroll
      for (int i = 0; i < 4; ++i)
#pragma unroll
        for (int jj = 0; jj < 4; ++jj)
          acc[i][jj] = __builtin_amdgcn_mfma_f32_16x16x32_bf16(af[i], wf[jj], acc[i][jj], 0, 0, 0);
    }
  }

  if (!j.tout) {
#pragma unroll
    for (int jj = 0; jj < 4; ++jj) {
      int col = n0 + wc * 64 + jj * 16 + lm;
      float bn = j.bias[col] * j.bscale;
#pragma unroll
      for (int i = 0; i < 4; ++i) {
        int mrow = m0 + wr * 64 + i * 16 + lq * 4;
#pragma unroll
        for (int r = 0; r < 4; ++r) {
          float cv = acc[i][jj][r] + bn;
          if (j.act) cv = 0.5f * cv * (1.0f + erff(cv * 0.70710678118f));
          j.C[(size_t)(mrow + r) * H_ + col] = f2bf(cv);
        }
      }
    }
  } else {
    int b = m0 >> 11;
    int sb = (m0 & (S_ - 1)) + wr * 64;
#pragma unroll
    for (int jj = 0; jj < 4; ++jj) {
      int col = n0 + wc * 64 + jj * 16 + lm;
      float bn = j.bias[col] * j.bscale;
      short* cp = j.C + ((size_t)(b * H_ + col)) * S_;
#pragma unroll
      for (int i = 0; i < 4; ++i) {
        int s = sb + i * 16 + lq * 4;
        s16x4 pk = {f2bf(acc[i][jj][0] + bn), f2bf(acc[i][jj][1] + bn),
                    f2bf(acc[i][jj][2] + bn), f2bf(acc[i][jj][3] + bn)};
        *(s16x4*)(cp + s) = pk;
      }
    }
  }
}

// ---------------------------------------------------------------------------
// Single GEMM, 128x64 tile (768 blocks = 3.0/CU): pw/o/post projections.
// 1D grid, XCD-swizzled (A row-panel locality).
// ---------------------------------------------------------------------------
__global__ __launch_bounds__(256) void gemm_n64(const short* __restrict__ A,
                                                const short* __restrict__ W,
                                                const float* __restrict__ bias,
                                                short* __restrict__ C, int act) {
  int d = blockIdx.x;
  int xcd = d & 7, s5 = d >> 3;            // s5 in [0,96)
  int nx = s5 % 12, ny = xcd + 8 * (s5 / 12);  // ny in [0,64)
  __shared__ short As[128 * 64];  // 16 KB
  __shared__ short Ws[64 * 64];   // 8 KB
  int tid = threadIdx.x, lane = tid & 63, w = tid >> 6;
  int wm = w >> 1, wn = w & 1, lm = lane & 15, lq = lane >> 4;
  int m0 = ny * 128, n0 = nx * 64;
  const short* gA = A + (size_t)(m0 + w * 32 + (lane >> 3)) * H_ + (lane & 7) * 8;
  const short* gW = W + (size_t)(n0 + w * 16 + (lane >> 3)) * H_ + (lane & 7) * 8;
  short* lA = As + w * 2048;  // 32 rows x 64
  short* lW = Ws + w * 1024;  // 16 rows x 64

  f32x4 acc[4][2];
#pragma unroll
  for (int i = 0; i < 4; ++i)
#pragma unroll
    for (int jj = 0; jj < 2; ++jj) acc[i][jj] = (f32x4){0.f, 0.f, 0.f, 0.f};

  for (int kt = 0; kt < H_; kt += 64) {
    __syncthreads();
#pragma unroll
    for (int c = 0; c < 4; ++c)
      gload16(gA + kt + (size_t)(c * 8) * H_, lA + c * 512);
#pragma unroll
    for (int c = 0; c < 2; ++c)
      gload16(gW + kt + (size_t)(c * 8) * H_, lW + c * 512);
    __syncthreads();
#pragma unroll
    for (int kk = 0; kk < 2; ++kk) {
      bf16x8 af[4], wf[2];
#pragma unroll
      for (int i = 0; i < 4; ++i)
        af[i] = *(const bf16x8*)&As[(wm * 64 + i * 16 + lm) * 64 + kk * 32 + lq * 8];
#pragma unroll
      for (int jj = 0; jj < 2; ++jj)
        wf[jj] = *(const bf16x8*)&Ws[(wn * 32 + jj * 16 + lm) * 64 + kk * 32 + lq * 8];
#pragma unroll
      for (int i = 0; i < 4; ++i)
#pragma unroll
        for (int jj = 0; jj < 2; ++jj)
          acc[i][jj] = __builtin_amdgcn_mfma_f32_16x16x32_bf16(af[i], wf[jj], acc[i][jj], 0, 0, 0);
    }
  }

#pragma unroll
  for (int jj = 0; jj < 2; ++jj) {
    int col = n0 + wn * 32 + jj * 16 + lm;
    float bn = bias[col];
#pragma unroll
    for (int i = 0; i < 4; ++i) {
      int mrow = m0 + wm * 64 + i * 16 + lq * 4;
#pragma unroll
      for (int r = 0; r < 4; ++r) {
        float cv = acc[i][jj][r] + bn;
        if (act) cv = 0.5f * cv * (1.0f + erff(cv * 0.70710678118f));
        C[(size_t)(mrow + r) * H_ + col] = f2bf(cv);
      }
    }
  }
}

// ---------------------------------------------------------------------------
// LayerNorm over last dim (H=768), bf16 in -> bf16 out
// ---------------------------------------------------------------------------
__global__ __launch_bounds__(256) void ln_bf(const short* __restrict__ X,
                                             short* __restrict__ Y,
                                             const float* __restrict__ g,
                                             const float* __restrict__ bb) {
  int row = blockIdx.x;
  size_t base = (size_t)row * H_;
  int h0 = threadIdx.x, h1 = h0 + 256, h2 = h0 + 512;
  float x0 = bf2f(X[base + h0]), x1 = bf2f(X[base + h1]), x2 = bf2f(X[base + h2]);
  float s = x0 + x1 + x2;
  float s2 = x0 * x0 + x1 * x1 + x2 * x2;
  for (int off = 32; off > 0; off >>= 1) {
    s += __shfl_down(s, off);
    s2 += __shfl_down(s2, off);
  }
  __shared__ float sa[4], sq[4], st[2];
  int wid = threadIdx.x >> 6, lane = threadIdx.x & 63;
  if (lane == 0) { sa[wid] = s; sq[wid] = s2; }
  __syncthreads();
  if (threadIdx.x == 0) {
    float ts = sa[0] + sa[1] + sa[2] + sa[3];
    float ts2 = sq[0] + sq[1] + sq[2] + sq[3];
    float mean = ts * (1.0f / H_);
    float var = ts2 * (1.0f / H_) - mean * mean;
    st[0] = mean;
    st[1] = rsqrtf(var + 1e-5f);
  }
  __syncthreads();
  float mean = st[0], rstd = st[1];
  Y[base + h0] = f2bf((x0 - mean) * rstd * g[h0] + bb[h0]);
  Y[base + h1] = f2bf((x1 - mean) * rstd * g[h1] + bb[h1]);
  Y[base + h2] = f2bf((x2 - mean) * rstd * g[h2] + bb[h2]);
}

// ---------------------------------------------------------------------------
// MFMA flash attention v6. Changes vs v5:
//  - Scores arrive pre-scaled (Wq,bq folded with 0.125*log2e): exp2 directly,
//    removing 32 v_mul per tile-wave.
//  - Double-buffered K/V LDS (48KB total): ONE barrier per 64-row tile
//    (write buf[t&1] -> barrier -> compute, next iter writes other buffer).
//  - 1D grid with XCD swizzle: the 16 q-blocks sharing one (b,head) K/V
//    slice land on one XCD (6 slices x 512KB = 3MB < 4MB L2/XCD).
// ---------------------------------------------------------------------------
__global__ __launch_bounds__(256) void attn6_k(const short* __restrict__ qb,
                                               const short* __restrict__ kb,
                                               const short* __restrict__ vtb,
                                               short* __restrict__ aob) {
  __shared__ short Ks[2][64 * 64];     // [sk][d] swizzled, 2 x 8 KB
  __shared__ short Vt[2][64 * 64];     // [d][sk] swizzled, 2 x 8 KB
  __shared__ short Ps[128 * 64];       // wave w rows [w*32, +32), swizzled, 16 KB
  int tid = threadIdx.x, lane = tid & 63, w = tid >> 6;  // w 0..3
  int lm = lane & 15, lq = lane >> 4;
  int lm7 = lm & 7;
  // XCD-swizzled decode: g=(b,n) group, all 16 q-blocks of g on one XCD
  int dd = blockIdx.x;
  int xcd = dd & 7, slot = dd >> 3;          // slot in [0,96)
  int g = xcd + 8 * (slot >> 4);             // g in [0,48)
  int qx = slot & 15;
  int b = g / NH_, n = g - b * NH_;
  int q0 = qx * 128;
  int hoff = n * HD_;

  // swizzled fragment slot offsets (in shorts): logical 16B-slot lq / lq+4
  int rb8 = (lq ^ lm7) << 3;
  int rb8x = rb8 ^ 32;

  bf16x8 qf[2][2];
#pragma unroll
  for (int qg = 0; qg < 2; ++qg) {
    const short* qrow = qb + ((size_t)(b * S_ + q0 + w * 32 + qg * 16 + lm)) * H_ + hoff;
    qf[qg][0] = *(const bf16x8*)(qrow + lq * 8);
    qf[qg][1] = *(const bf16x8*)(qrow + 32 + lq * 8);
  }

  // ones A-fragment (bf16 1.0) for MFMA row-sum of P
  bf16x8 onef = {0x3F80, 0x3F80, 0x3F80, 0x3F80, 0x3F80, 0x3F80, 0x3F80, 0x3F80};
  f32x4 ls[2];
  ls[0] = (f32x4){0.f, 0.f, 0.f, 0.f};
  ls[1] = (f32x4){0.f, 0.f, 0.f, 0.f};

  f32x4 o[4][2];
#pragma unroll
  for (int i = 0; i < 4; ++i)
#pragma unroll
    for (int qg = 0; qg < 2; ++qg) o[i][qg] = (f32x4){0.f, 0.f, 0.f, 0.f};

  // staging: row = tid>>2 (0..63), 2x16B each of K,V at logical slots 2j, 2j+1
  int r0 = tid >> 2;
  int c0 = (tid & 3) * 16;
  int sl = (tid & 3) * 2;
  int sw0 = r0 * 64 + ((sl ^ (r0 & 7)) << 3);
  int sw1 = r0 * 64 + (((sl ^ 1) ^ (r0 & 7)) << 3);
  const short* kg = kb + ((size_t)(b * S_)) * H_ + hoff;
  const short* vg = vtb + ((size_t)(b * H_ + hoff)) * S_;

  bf16x8 kv0 = *(const bf16x8*)(kg + (size_t)r0 * H_ + c0);
  bf16x8 kv1 = *(const bf16x8*)(kg + (size_t)r0 * H_ + c0 + 8);
  bf16x8 vv0 = *(const bf16x8*)(vg + (size_t)r0 * S_ + c0);
  bf16x8 vv1 = *(const bf16x8*)(vg + (size_t)r0 * S_ + c0 + 8);

  for (int kt = 0, pb = 0; kt < S_; kt += 64, pb ^= 1) {
    short* Kw = &Ks[pb][0];
    short* Vw = &Vt[pb][0];
    // write this tile's staged regs into buf[pb]; previous iter's readers are
    // on buf[pb^1], so no pre-write barrier needed.
    *(bf16x8*)&Kw[sw0] = kv0;
    *(bf16x8*)&Kw[sw1] = kv1;
    *(bf16x8*)&Vw[sw0] = vv0;
    *(bf16x8*)&Vw[sw1] = vv1;
    __syncthreads();
    if (kt + 64 < S_) {
      kv0 = *(const bf16x8*)(kg + (size_t)(kt + 64 + r0) * H_ + c0);
      kv1 = *(const bf16x8*)(kg + (size_t)(kt + 64 + r0) * H_ + c0 + 8);
      vv0 = *(const bf16x8*)(vg + (size_t)r0 * S_ + kt + 64 + c0);
      vv1 = *(const bf16x8*)(vg + (size_t)r0 * S_ + kt + 64 + c0 + 8);
    }

    // ---- S^T[sk][q]: sk = ni*16 + lq*4 + r, q = lm (per q-group) ----
    f32x4 st[4][2];
#pragma unroll
    for (int ni = 0; ni < 4; ++ni) {
      int krow = (ni * 16 + lm) * 64;
      bf16x8 ka0 = *(const bf16x8*)&Kw[krow + rb8];
      bf16x8 ka1 = *(const bf16x8*)&Kw[krow + rb8x];
#pragma unroll
      for (int qg = 0; qg < 2; ++qg) {
        f32x4 z = (f32x4){0.f, 0.f, 0.f, 0.f};
        z = __builtin_amdgcn_mfma_f32_16x16x32_bf16(ka0, qf[qg][0], z, 0, 0, 0);
        st[ni][qg] = __builtin_amdgcn_mfma_f32_16x16x32_bf16(ka1, qf[qg][1], z, 0, 0, 0);
      }
    }

    // ---- softmax numerator + P pack via v_perm (sum via MFMA below) ----
#pragma unroll
    for (int qg = 0; qg < 2; ++qg) {
      int prow = (w * 32 + qg * 16 + lm) * 64 + (lq & 1) * 4;
      int lqh = lq >> 1;
#pragma unroll
      for (int ni = 0; ni < 4; ++ni) {
        float p0 = exp2f(st[ni][qg][0]);
        float p1 = exp2f(st[ni][qg][1]);
        float p2 = exp2f(st[ni][qg][2]);
        float p3 = exp2f(st[ni][qg][3]);
        u32x2 pk = {bfpack(p0, p1), bfpack(p2, p3)};
        *(u32x2*)&Ps[prow + (((2 * ni + lqh) ^ lm7) << 3)] = pk;
      }
    }

    // ---- O^T += V^T P^T ; denominator += 1^T P^T (matrix pipe) ----
    bf16x8 pf[2][2];
#pragma unroll
    for (int qg = 0; qg < 2; ++qg) {
      int prow = (w * 32 + qg * 16 + lm) * 64;
      pf[qg][0] = *(const bf16x8*)&Ps[prow + rb8];
      pf[qg][1] = *(const bf16x8*)&Ps[prow + rb8x];
      ls[qg] = __builtin_amdgcn_mfma_f32_16x16x32_bf16(onef, pf[qg][0], ls[qg], 0, 0, 0);
      ls[qg] = __builtin_amdgcn_mfma_f32_16x16x32_bf16(onef, pf[qg][1], ls[qg], 0, 0, 0);
    }
#pragma unroll
    for (int nd = 0; nd < 4; ++nd) {
      int vrow = (nd * 16 + lm) * 64;
      bf16x8 va0 = *(const bf16x8*)&Vw[vrow + rb8];
      bf16x8 va1 = *(const bf16x8*)&Vw[vrow + rb8x];
#pragma unroll
      for (int qg = 0; qg < 2; ++qg) {
        o[nd][qg] = __builtin_amdgcn_mfma_f32_16x16x32_bf16(va0, pf[qg][0], o[nd][qg], 0, 0, 0);
        o[nd][qg] = __builtin_amdgcn_mfma_f32_16x16x32_bf16(va1, pf[qg][1], o[nd][qg], 0, 0, 0);
      }
    }
  }

  // epilogue: q row = q0 + w*32 + qg*16 + lm; d = nd*16 + lq*4 + r
#pragma unroll
  for (int qg = 0; qg < 2; ++qg) {
    float inv = 1.0f / ls[qg][0];
    short* orow = aob + ((size_t)(b * S_ + q0 + w * 32 + qg * 16 + lm)) * H_ + hoff;
#pragma unroll
    for (int nd = 0; nd < 4; ++nd) {
      s16x4 pk = {f2bf(o[nd][qg][0] * inv), f2bf(o[nd][qg][1] * inv),
                  f2bf(o[nd][qg][2] * inv), f2bf(o[nd][qg][3] * inv)};
      *(s16x4*)(orow + nd * 16 + lq * 4) = pk;
    }
  }
}

// ---------------------------------------------------------------------------
// gate + masked residual + aux partials. 192 thr, x4 vectorized.
// ---------------------------------------------------------------------------
__global__ __launch_bounds__(192) void gate_out_k(const float* __restrict__ x,
                                                  const short* __restrict__ br,
                                                  const short* __restrict__ inj,
                                                  const int* __restrict__ mask,
                                                  const float* __restrict__ Wg,
                                                  const float* __restrict__ bg,
                                                  float* __restrict__ out,
                                                  float* __restrict__ paux) {
  int row = blockIdx.x;
  int b = row >> 11;
  size_t base = (size_t)row * H_;
  int h = threadIdx.x * 4;
  float4 xv = *(const float4*)(x + base + h);
  s16x4 brv = *(const s16x4*)(br + base + h);
  s16x4 inv = *(const s16x4*)(inj + base + h);
  float4 wg0 = *(const float4*)(Wg + h);
  float4 wg1 = *(const float4*)(Wg + H_ + h);
  float b0 = bf2f(brv.x), b1 = bf2f(brv.y), b2 = bf2f(brv.z), b3 = bf2f(brv.w);
  float dot = xv.x * wg0.x + xv.y * wg0.y + xv.z * wg0.z + xv.w * wg0.w
            + b0 * wg1.x + b1 * wg1.y + b2 * wg1.z + b3 * wg1.w;
  float d0 = b0 - xv.x, d1 = b1 - xv.y, d2 = b2 - xv.z, d3 = b3 - xv.w;
  float aux = d0 * d0 + d1 * d1 + d2 * d2 + d3 * d3;
  for (int off = 32; off > 0; off >>= 1) {
    dot += __shfl_down(dot, off);
    aux += __shfl_down(aux, off);
  }
  __shared__ float sd[3], sx[3], gsh[2];
  int wid = threadIdx.x >> 6, lane = threadIdx.x & 63;
  if (lane == 0) { sd[wid] = dot; sx[wid] = aux; }
  __syncthreads();
  if (threadIdx.x == 0) {
    float td = sd[0] + sd[1] + sd[2];
    float ta = sx[0] + sx[1] + sx[2];
    gsh[0] = 1.0f / (1.0f + expf(-(td + bg[0])));
    gsh[1] = ta;
  }
  __syncthreads();
  float mf = (mask[b] != 0) ? 1.0f : 0.0f;
  float gm = gsh[0] * mf;
  float v0 = bf2f(inv.x), v1 = bf2f(inv.y), v2 = bf2f(inv.z), v3 = bf2f(inv.w);
  float e0 = __expf(2.f * v0), e1 = __expf(2.f * v1), e2 = __expf(2.f * v2), e3 = __expf(2.f * v3);
  float4 ov;
  ov.x = xv.x + gm * ((e0 - 1.f) / (e0 + 1.f));
  ov.y = xv.y + gm * ((e1 - 1.f) / (e1 + 1.f));
  ov.z = xv.z + gm * ((e2 - 1.f) / (e2 + 1.f));
  ov.w = xv.w + gm * ((e3 - 1.f) / (e3 + 1.f));
  *(float4*)(out + base + h) = ov;
  if (threadIdx.x == 0) paux[row] = mf * gsh[1];
}

__global__ __launch_bounds__(256) void aux_reduce_k(const float* __restrict__ paux,
                                                    const int* __restrict__ mask,
                                                    float* __restrict__ outp) {
  float s = 0.f;
  for (int i = threadIdx.x; i < NROWS; i += 256) s += paux[i];
  for (int off = 32; off > 0; off >>= 1) s += __shfl_down(s, off);
  __shared__ float sw[4];
  int wid = threadIdx.x >> 6, lane = threadIdx.x & 63;
  if (lane == 0) sw[wid] = s;
  __syncthreads();
  if (threadIdx.x == 0) {
    float t = sw[0] + sw[1] + sw[2] + sw[3];
    int nm = (mask[0] != 0) + (mask[1] != 0) + (mask[2] != 0) + (mask[3] != 0);
    if (nm < 1) nm = 1;
    outp[0] = t / ((float)nm * (float)(S_ * H_));
  }
}

// ---------------------------------------------------------------------------
extern "C" void kernel_launch(void* const* d_in, const int* in_sizes, int n_in,
                              void* d_out, int out_size, void* d_ws, size_t ws_size,
                              hipStream_t stream) {
  const float* x     = (const float*)d_in[0];
  const float* prev  = (const float*)d_in[1];
  const int*   mask  = (const int*)d_in[2];
  const float* dw_w  = (const float*)d_in[3];
  const float* dw_b  = (const float*)d_in[4];
  const float* pw_w  = (const float*)d_in[5];
  const float* pw_b  = (const float*)d_in[6];
  const float* cn_g  = (const float*)d_in[7];
  const float* cn_b  = (const float*)d_in[8];
  const float* Wq    = (const float*)d_in[9];
  const float* bq    = (const float*)d_in[10];
  const float* Wk    = (const float*)d_in[11];
  const float* bk    = (const float*)d_in[12];
  const float* Wv    = (const float*)d_in[13];
  const float* bv    = (const float*)d_in[14];
  const float* Wo    = (const float*)d_in[15];
  const float* bo    = (const float*)d_in[16];
  const float* pn_g  = (const float*)d_in[17];
  const float* pn_b  = (const float*)d_in[18];
  const float* Wpost = (const float*)d_in[19];
  const float* bpost = (const float*)d_in[20];
  const float* Wg    = (const float*)d_in[21];
  const float* bg    = (const float*)d_in[22];
  float* out = (float*)d_out;

  short* B0 = (short*)d_ws;     // xb
  short* B1 = B0 + BSH;         // dwo -> qb
  short* B2 = B1 + BSH;         // gelu-out -> aob
  short* B3 = B2 + BSH;         // bridged (until gate)
  short* B4 = B3 + BSH;         // kb -> ao_proj -> pn
  short* B5 = B4 + BSH;         // vtb -> injb
  short* WW = B5 + BSH;         // 6 bf16 weights [pw,q,k,v,o,post]
  float* paux = (float*)(WW + 6 * WSZ);

  const float C1 = 0.1803368802f;  // 0.125 * log2(e), folded into Wq/bq

  GemmJob jq = {B0, WW + WSZ,     bq, B1, 0, 0, C1};
  GemmJob jk = {B3, WW + 2 * WSZ, bk, B4, 0, 0, 1.0f};
  GemmJob jv = {B3, WW + 3 * WSZ, bv, B5, 0, 1, 1.0f};

  cvt6_k<<<6 * WSZ / 1024, 256, 0, stream>>>(pw_w, Wq, Wk, Wv, Wo, Wpost, WW);
  cvt_x_k<<<BSH / 1024, 256, 0, stream>>>(x, B0);
  dwconv_k<<<NROWS, 192, 0, stream>>>(prev, dw_w, dw_b, B1);
  gemm_n64<<<768, 256, 0, stream>>>(B1, WW, pw_b, B2, 1);                  // pw + GELU
  ln_bf<<<NROWS, 256, 0, stream>>>(B2, B3, cn_g, cn_b);                    // bridged
  gemm_bf2<<<1152, 256, 0, stream>>>(jq, jk, jv);                          // Q,K,V grouped
  attn6_k<<<768, 256, 0, stream>>>(B1, B4, B5, B2);                        // -> aob
  gemm_n64<<<768, 256, 0, stream>>>(B2, WW + 4 * WSZ, bo, B4, 0);          // o-proj
  ln_bf<<<NROWS, 256, 0, stream>>>(B4, B4, pn_g, pn_b);                    // pn
  gemm_n64<<<768, 256, 0, stream>>>(B4, WW + 5 * WSZ, bpost, B5, 0);       // post
  gate_out_k<<<NROWS, 192, 0, stream>>>(x, B3, B5, mask, Wg, bg, out, paux);
  aux_reduce_k<<<1, 256, 0, stream>>>(paux, mask, out + BSH);
}